// Round 16
// baseline (119.691 us; speedup 1.0000x reference)
//
#include <hip/hip_runtime.h>
#include <stdint.h>

// ---------------------------------------------------------------------------
// UnifiedEnergyFunction: total/hopfield/consistency/regularization scalars.
//   hopfield = mean_b( -logsumexp_n( z[b,:] . M[n,:] ) )
//   consistency = mean_b ||z - z_next||^2   (f32 inputs, unaffected by fp8)
//   regularization = 0.01 * mean_b ||z||^2
// v16: 4 waves/SIMD. The 2-wave regime is additive (blocking matrix pipe
// re-syncs co-resident waves into in-phase -> v13 44%+43%, v15 sleep null).
// Live set cut to ~114 regs so __launch_bounds__(256,4) doesn't spill
// (v12's failure): single-buffered af (v9's WAR-safe reload), single acc
// with INITC const as C-in (no per-group init movs), self-drain hidden by
// 3 other waves. Grid 1024 = 16 bblk x 16 nsplit x 4 q; 4 blocks/CU.
// ---------------------------------------------------------------------------

typedef __attribute__((ext_vector_type(8))) int   v8i;
typedef __attribute__((ext_vector_type(4))) float f32x4;

#define N_PAT  65536
#define D_DIM  256
#define B_ROWS 4096
#define NSPLIT 16                 // M ranges (2 per XCD, 1MB fp8 each)
#define NRANGE (N_PAT / NSPLIT)   // 4096 rows per range
#define SPR    (NRANGE / 16)      // 256 16-row fragment groups per range
#define SPERW4 (SPR / 4)          // 64 groups per wave (q 4-way split)
#define BBLK   256                // b rows per block (4 waves x 64)
#define NPART  (NSPLIT * 4)       // 64 partials per b row
#define SHIFT2 69.0f              // fixed shift in log2 domain (~48 nats)
#define LOG2E  1.44269504f
#define LN2    0.69314718f
#define SCL1   0x7F7F7F7F         // E8M0 scale bytes = 127 -> 1.0

// workspace layout (bytes)
#define WS_M_OFF   ((size_t)0)
#define WS_M_BYTES ((size_t)N_PAT * D_DIM)          // 16 MB packed fp8 M
#define WS_Z_OFF   (WS_M_OFF + WS_M_BYTES)
#define WS_Z_BYTES ((size_t)B_ROWS * D_DIM)         // 1 MB fp8 z*log2e (row-major)
#define WS_LSE_OFF (WS_Z_OFF + WS_Z_BYTES)
#define WS_LSE_BYTES ((size_t)B_ROWS * NPART * 4)   // 1 MB partial S
#define WS_CSS_OFF (WS_LSE_OFF + WS_LSE_BYTES)
#define WS_ZSS_OFF (WS_CSS_OFF + (size_t)512 * 4)

__device__ __forceinline__ float fexp2(float x) {
  return __builtin_amdgcn_exp2f(x);   // v_exp_f32 (hardware base-2 exp)
}

__device__ __forceinline__ int pk4_fp8(float a, float b, float c, float d) {
  int r = __builtin_amdgcn_cvt_pk_fp8_f32(a, b, 0, false);   // bytes 0,1
  r = __builtin_amdgcn_cvt_pk_fp8_f32(c, d, r, true);        // bytes 2,3
  return r;
}

__device__ __forceinline__ float waveRedAdd(float v) {
  #pragma unroll
  for (int o = 32; o > 0; o >>= 1) v += __shfl_down(v, o, 64);
  return v;
}

// ---------------------------------------------------------------- kernel A1
// M f32 -> fp8 e4m3 in 16x16x128 A-fragment order, coalesced reads.
// Element M[row][k] -> dword (row>>4)*1024 + (k>>7)*512 +
//   (((k>>5)&3)*16 + (row&15))*8 + ((k>>2)&7)  [byte k&3]
__global__ void convert_m_kernel(const float* __restrict__ src, int* __restrict__ dst) {
  const int c = blockIdx.x * 256 + threadIdx.x;   // chunk 0..2^21-1 (grid 8192)
  const int row = c >> 5;
  const int j = c & 31;                           // which 8-elem chunk of the row
  const float* sp = src + (size_t)row * D_DIM + j * 8;
  const float4 x = *(const float4*)(sp);
  const float4 y = *(const float4*)(sp + 4);
  int2 o;
  o.x = pk4_fp8(x.x, x.y, x.z, x.w);
  o.y = pk4_fp8(y.x, y.y, y.z, y.w);
  const size_t dw = (size_t)(row >> 4) * 1024 + (j >> 4) * 512 +
                    (((j >> 2) & 3) * 16 + (row & 15)) * 8 + (j & 3) * 2;
  *(int2*)(dst + dw) = o;
}

// ---------------------------------------------------------------- kernel A2
// z -> fp8 of z*log2(e) (row-major), plus partials of ||z-zn||^2, ||z||^2
__global__ void prep_z_kernel(const float* __restrict__ z, const float* __restrict__ zn,
                              int* __restrict__ z8, float* __restrict__ css,
                              float* __restrict__ zss) {
  int t = blockIdx.x * 256 + threadIdx.x;  // 512 blocks x 256 = exactly B*D/8
  const float* az = z + (size_t)t * 8;
  const float* an = zn + (size_t)t * 8;
  float4 z0 = *(const float4*)(az), z1 = *(const float4*)(az + 4);
  float4 n0 = *(const float4*)(an), n1 = *(const float4*)(an + 4);
  float zv[8] = {z0.x, z0.y, z0.z, z0.w, z1.x, z1.y, z1.z, z1.w};
  float nv[8] = {n0.x, n0.y, n0.z, n0.w, n1.x, n1.y, n1.z, n1.w};
  float cs = 0.f, zs = 0.f;
  #pragma unroll
  for (int j = 0; j < 8; ++j) {
    float d = zv[j] - nv[j];
    cs += d * d;
    zs += zv[j] * zv[j];
  }
  int2 o;
  o.x = pk4_fp8(zv[0] * LOG2E, zv[1] * LOG2E, zv[2] * LOG2E, zv[3] * LOG2E);
  o.y = pk4_fp8(zv[4] * LOG2E, zv[5] * LOG2E, zv[6] * LOG2E, zv[7] * LOG2E);
  *(int2*)(z8 + (size_t)t * 2) = o;        // row-major fp8, 8 bytes/thread

  __shared__ float rc[4], rz[4];
  cs = waveRedAdd(cs);
  zs = waveRedAdd(zs);
  int w = threadIdx.x >> 6, lane = threadIdx.x & 63;
  if (lane == 0) { rc[w] = cs; rz[w] = zs; }
  __syncthreads();
  if (threadIdx.x == 0) {
    css[blockIdx.x] = rc[0] + rc[1] + rc[2] + rc[3];
    zss[blockIdx.x] = rz[0] + rz[1] + rz[2] + rz[3];
  }
}

// ---------------------------------------------------------------- kernel B
// Barrier-free flash-LSE, MX-fp8 16x16x128 (scale=1.0), 1024 blocks x 4
// waves, 4 blocks/CU = 4 waves/SIMD. Block = (bblk, nsplit, q); wave w owns
// b-cols [bblk*256 + w*64, +64) and groups s = nsplit*256 + q + 4*j.
// Per group: {8 MFMA (INITC as C-in for kh=0) | reload af (next group) |
//             16 exp2 self-drain (hidden by the other 3 waves' MFMAs)}.
__global__ __launch_bounds__(256, 4) void lse_kernel(const int* __restrict__ Mp,
                                                     const int* __restrict__ z8,
                                                     float* __restrict__ lsep) {
  const int bid = blockIdx.x;             // 1024 blocks
  const int xcd = bid & 7;
  const int g = bid >> 3;                 // 0..127
  const int half = g >> 6;
  const int nsplit = xcd * 2 + half;      // 2 ranges live per XCD
  const int rem = g & 63;
  const int bblk = rem & 15;              // 16 b-blocks of 256 rows
  const int q = rem >> 4;                 // group residue mod 4

  const int tid = threadIdx.x;
  const int w = tid >> 6;
  const int lane = tid & 63;
  const int l15 = lane & 15;
  const int grp = lane >> 4;

  // hoist z fragments: 4 b-subtiles x 2 k-halves = 64 regs (AGPR-resident)
  v8i zf[4][2];
  const int brow0 = bblk * BBLK + w * 64;
  #pragma unroll
  for (int bt = 0; bt < 4; ++bt) {
    #pragma unroll
    for (int kh = 0; kh < 2; ++kh) {
      int row = brow0 + bt * 16 + l15;
      zf[bt][kh] = *(const v8i*)(z8 + (size_t)row * 64 + kh * 32 + grp * 8);
    }
  }

  // fragment stream: s = nsplit*256 + q + 4*j; dword(s,kh,lane)=s*1024+kh*512+lane*8
  const int* pj = Mp + (size_t)(nsplit * SPR + q) * 1024 + lane * 8;

  const f32x4 INITC = {-SHIFT2, -SHIFT2, -SHIFT2, -SHIFT2};
  float ssum[4] = {0.f, 0.f, 0.f, 0.f};
  f32x4 acc[4];
  v8i af[2];

  // prologue: group 0's fragments in flight
  #pragma unroll
  for (int kh = 0; kh < 2; ++kh) af[kh] = *(const v8i*)(pj + kh * 512);

  #pragma unroll 1
  for (int j = 0; j < SPERW4; ++j) {
    const int* pn = pj + 4096;            // next group (s += 4)

    __builtin_amdgcn_s_setprio(1);
    #pragma unroll
    for (int bt = 0; bt < 4; ++bt)        // kh=0: INITC as C-in (no init movs)
      acc[bt] = __builtin_amdgcn_mfma_scale_f32_16x16x128_f8f6f4(
          af[0], zf[bt][0], INITC, 0, 0, 0, SCL1, 0, SCL1);
    #pragma unroll
    for (int bt = 0; bt < 4; ++bt)        // kh=1: accumulate
      acc[bt] = __builtin_amdgcn_mfma_scale_f32_16x16x128_f8f6f4(
          af[1], zf[bt][1], acc[bt], 0, 0, 0, SCL1, 0, SCL1);
    __builtin_amdgcn_s_setprio(0);

    // reload af for the NEXT group (WAR-safe: loads issue after the MFMAs
    // that read af; v9-proven pattern). Tail overshoot lands in z8: harmless.
    #pragma unroll
    for (int kh = 0; kh < 2; ++kh) af[kh] = *(const v8i*)(pn + kh * 512);

    // self-drain: acc = log2-logit - SHIFT2; the wave stalls on its own
    // MFMA results, but the other 3 waves on this SIMD keep the pipes fed.
    #pragma unroll
    for (int bt = 0; bt < 4; ++bt)
      ssum[bt] += (fexp2(acc[bt][0]) + fexp2(acc[bt][1])) +
                  (fexp2(acc[bt][2]) + fexp2(acc[bt][3]));

    pj = pn;
  }

  // 4 lane-groups hold different n-rows of each fragment for the same b-col
  #pragma unroll
  for (int bt = 0; bt < 4; ++bt) {
    ssum[bt] += __shfl_xor(ssum[bt], 16, 64);
    ssum[bt] += __shfl_xor(ssum[bt], 32, 64);
  }
  if (grp == 0) {
    #pragma unroll
    for (int bt = 0; bt < 4; ++bt) {
      int b = brow0 + bt * 16 + l15;
      lsep[(size_t)b * NPART + nsplit * 4 + q] = ssum[bt];
    }
  }
}

// ---------------------------------------------------------------- kernel C
__global__ void finalize_kernel(const float* __restrict__ lsep, const float* __restrict__ css,
                                const float* __restrict__ zss, float* __restrict__ out) {
  __shared__ float r1[16], r2[16], r3[16];
  int tid = threadIdx.x;  // 1024
  float sum_lse = 0.f;
  for (int r = tid; r < B_ROWS; r += 1024) {
    float S = 0.f;
    #pragma unroll
    for (int i = 0; i < NPART; ++i) S += lsep[(size_t)r * NPART + i];
    sum_lse += SHIFT2 * LN2 + logf(S);   // back to nats
  }
  float cs = 0.f, zs = 0.f;
  if (tid < 512) { cs = css[tid]; zs = zss[tid]; }

  sum_lse = waveRedAdd(sum_lse);
  cs = waveRedAdd(cs);
  zs = waveRedAdd(zs);
  int w = tid >> 6, lane = tid & 63;
  if (lane == 0) { r1[w] = sum_lse; r2[w] = cs; r3[w] = zs; }
  __syncthreads();
  if (tid == 0) {
    float sl = 0.f, sc = 0.f, sz = 0.f;
    #pragma unroll
    for (int i = 0; i < 16; ++i) { sl += r1[i]; sc += r2[i]; sz += r3[i]; }
    float hop = -sl / (float)B_ROWS;
    float cons = sc / (float)B_ROWS;
    float reg = 0.01f * sz / (float)B_ROWS;
    out[0] = hop + cons + reg;
    out[1] = hop;
    out[2] = cons;
    out[3] = reg;
  }
}

// ---------------------------------------------------------------------------
extern "C" void kernel_launch(void* const* d_in, const int* in_sizes, int n_in,
                              void* d_out, int out_size, void* d_ws, size_t ws_size,
                              hipStream_t stream) {
  (void)in_sizes; (void)n_in; (void)out_size; (void)ws_size;
  const float* z  = (const float*)d_in[0];
  const float* zn = (const float*)d_in[1];
  const float* M  = (const float*)d_in[2];
  char* ws = (char*)d_ws;
  int* Mp  = (int*)(ws + WS_M_OFF);
  int* z8  = (int*)(ws + WS_Z_OFF);
  float* lsep = (float*)(ws + WS_LSE_OFF);
  float* css = (float*)(ws + WS_CSS_OFF);
  float* zss = (float*)(ws + WS_ZSS_OFF);

  convert_m_kernel<<<8192, 256, 0, stream>>>(M, Mp);
  prep_z_kernel<<<512, 256, 0, stream>>>(z, zn, z8, css, zss);
  lse_kernel<<<1024, 256, 0, stream>>>(Mp, z8, lsep);
  finalize_kernel<<<1, 1024, 0, stream>>>(lsep, css, zss, (float*)d_out);
}

// Round 17
// 101.423 us; speedup vs baseline: 1.1801x; 1.1801x over previous
//
#include <hip/hip_runtime.h>
#include <stdint.h>

// ---------------------------------------------------------------------------
// UnifiedEnergyFunction: total/hopfield/consistency/regularization scalars.
//   hopfield = mean_b( -logsumexp_n( z[b,:] . M[n,:] ) )
//   consistency = mean_b ||z - z_next||^2
//   regularization = 0.01 * mean_b ||z||^2
// v17: WAVE SPECIALIZATION (m114 regime). v13/v16 showed every-wave-alternates
// is additive (MFMA 44/39% + VALU 43/38%) no matter the occupancy, because
// same-wave-id waves on a SIMD are phase-locked by construction. Here waves
// 0-3 are pure-MFMA producers, waves 4-7 pure-exp2 consumers (same SIMD pairs
// via round-robin wave->SIMD). Handoff: 2x4KB LDS buffers per pair, one
// barrier per group. MX-fp8 16x16x128 stream otherwise = v13.
// finalize split in two (single-block tail was ~10us serial).
// ---------------------------------------------------------------------------

typedef __attribute__((ext_vector_type(8))) int   v8i;
typedef __attribute__((ext_vector_type(4))) float f32x4;

#define N_PAT  65536
#define D_DIM  256
#define B_ROWS 4096
#define NSPLIT 16                 // M ranges (2 per XCD, 1MB fp8 each)
#define NRANGE (N_PAT / NSPLIT)   // 4096 rows per range
#define SPR    (NRANGE / 16)      // 256 16-row fragment groups per range
#define BBLK   256                // b rows per block (4 producers x 64)
#define SHIFT2 69.0f              // fixed shift in log2 domain (~48 nats)
#define LOG2E  1.44269504f
#define LN2    0.69314718f
#define SCL1   0x7F7F7F7F         // E8M0 scale bytes = 127 -> 1.0

// workspace layout (bytes)
#define WS_M_OFF   ((size_t)0)
#define WS_M_BYTES ((size_t)N_PAT * D_DIM)          // 16 MB packed fp8 M
#define WS_Z_OFF   (WS_M_OFF + WS_M_BYTES)
#define WS_Z_BYTES ((size_t)B_ROWS * D_DIM)         // 1 MB fp8 z*log2e
#define WS_LSE_OFF (WS_Z_OFF + WS_Z_BYTES)
#define WS_LSE_BYTES ((size_t)B_ROWS * NSPLIT * 4)  // 256KB partial S
#define WS_ROW_OFF (WS_LSE_OFF + WS_LSE_BYTES)
#define WS_ROW_BYTES ((size_t)B_ROWS * 4)           // 16KB per-row lse
#define WS_CSS_OFF (WS_ROW_OFF + WS_ROW_BYTES)
#define WS_ZSS_OFF (WS_CSS_OFF + (size_t)512 * 4)

__device__ __forceinline__ float fexp2(float x) {
  return __builtin_amdgcn_exp2f(x);   // v_exp_f32 (hardware base-2 exp)
}

__device__ __forceinline__ int pk4_fp8(float a, float b, float c, float d) {
  int r = __builtin_amdgcn_cvt_pk_fp8_f32(a, b, 0, false);   // bytes 0,1
  r = __builtin_amdgcn_cvt_pk_fp8_f32(c, d, r, true);        // bytes 2,3
  return r;
}

__device__ __forceinline__ float waveRedAdd(float v) {
  #pragma unroll
  for (int o = 32; o > 0; o >>= 1) v += __shfl_down(v, o, 64);
  return v;
}

// ---------------------------------------------------------------- kernel A1
// M f32 -> fp8 e4m3 in 16x16x128 A-fragment order, coalesced reads.
// Element M[row][k] -> dword (row>>4)*1024 + (k>>7)*512 +
//   (((k>>5)&3)*16 + (row&15))*8 + ((k>>2)&7)  [byte k&3]
__global__ void convert_m_kernel(const float* __restrict__ src, int* __restrict__ dst) {
  const int c = blockIdx.x * 256 + threadIdx.x;   // chunk 0..2^21-1 (grid 8192)
  const int row = c >> 5;
  const int j = c & 31;                           // which 8-elem chunk of the row
  const float* sp = src + (size_t)row * D_DIM + j * 8;
  const float4 x = *(const float4*)(sp);
  const float4 y = *(const float4*)(sp + 4);
  int2 o;
  o.x = pk4_fp8(x.x, x.y, x.z, x.w);
  o.y = pk4_fp8(y.x, y.y, y.z, y.w);
  const size_t dw = (size_t)(row >> 4) * 1024 + (j >> 4) * 512 +
                    (((j >> 2) & 3) * 16 + (row & 15)) * 8 + (j & 3) * 2;
  *(int2*)(dst + dw) = o;
}

// ---------------------------------------------------------------- kernel A2
// z -> fp8 of z*log2(e) (row-major), plus partials of ||z-zn||^2, ||z||^2
__global__ void prep_z_kernel(const float* __restrict__ z, const float* __restrict__ zn,
                              int* __restrict__ z8, float* __restrict__ css,
                              float* __restrict__ zss) {
  int t = blockIdx.x * 256 + threadIdx.x;  // 512 blocks x 256 = exactly B*D/8
  const float* az = z + (size_t)t * 8;
  const float* an = zn + (size_t)t * 8;
  float4 z0 = *(const float4*)(az), z1 = *(const float4*)(az + 4);
  float4 n0 = *(const float4*)(an), n1 = *(const float4*)(an + 4);
  float zv[8] = {z0.x, z0.y, z0.z, z0.w, z1.x, z1.y, z1.z, z1.w};
  float nv[8] = {n0.x, n0.y, n0.z, n0.w, n1.x, n1.y, n1.z, n1.w};
  float cs = 0.f, zs = 0.f;
  #pragma unroll
  for (int j = 0; j < 8; ++j) {
    float d = zv[j] - nv[j];
    cs += d * d;
    zs += zv[j] * zv[j];
  }
  int2 o;
  o.x = pk4_fp8(zv[0] * LOG2E, zv[1] * LOG2E, zv[2] * LOG2E, zv[3] * LOG2E);
  o.y = pk4_fp8(zv[4] * LOG2E, zv[5] * LOG2E, zv[6] * LOG2E, zv[7] * LOG2E);
  *(int2*)(z8 + (size_t)t * 2) = o;        // row-major fp8, 8 bytes/thread

  __shared__ float rc[4], rz[4];
  cs = waveRedAdd(cs);
  zs = waveRedAdd(zs);
  int w = threadIdx.x >> 6, lane = threadIdx.x & 63;
  if (lane == 0) { rc[w] = cs; rz[w] = zs; }
  __syncthreads();
  if (threadIdx.x == 0) {
    css[blockIdx.x] = rc[0] + rc[1] + rc[2] + rc[3];
    zss[blockIdx.x] = rz[0] + rz[1] + rz[2] + rz[3];
  }
}

// ---------------------------------------------------------------- kernel B
// Producer/consumer flash-LSE. 256 blocks x 512 threads (1 block/CU).
// Waves 0-3: producers — pure MFMA stream over 256 groups x 64 b-cols each,
//   writing acc to LDS buf[p][j&1] (contiguous 1KB/instr, conflict-free).
// Waves 4-7: consumers — pure exp2 drain of buf[p][(j-1)&1].
// Wave w and w+4 share a SIMD (round-robin mapping) -> each SIMD runs one
// pure-MFMA and one pure-VALU stream concurrently (m114: max, not sum).
// One barrier per group enforces the double-buffer handoff.
__global__ __launch_bounds__(512, 2) void lse_kernel(const int* __restrict__ Mp,
                                                     const int* __restrict__ z8,
                                                     float* __restrict__ lsep) {
  __shared__ float hand[4][2][4][64][4];  // [prod][buf][bt][lane][4] = 32KB

  const int bid = blockIdx.x;             // 256 blocks
  const int xcd = bid & 7;
  const int g = bid >> 3;                 // 0..31
  const int bblk = g & 15;                // 16 b-blocks of 256 rows
  const int half = g >> 4;
  const int nsplit = xcd * 2 + half;      // 2 ranges live per XCD (proven)

  const int tid = threadIdx.x;
  const int w = tid >> 6;                 // 0..7
  const int lane = tid & 63;
  const int l15 = lane & 15;
  const int grp = lane >> 4;
  const int role = w >> 2;                // 0 = producer, 1 = consumer
  const int p = w & 3;                    // pair id (same-SIMD partner w+4)

  const int brow0 = bblk * BBLK + p * 64;

  if (role == 0) {
    // ---------------- producer: pure MFMA stream ----------------
    v8i zf[4][2];
    #pragma unroll
    for (int bt = 0; bt < 4; ++bt) {
      #pragma unroll
      for (int kh = 0; kh < 2; ++kh) {
        int row = brow0 + bt * 16 + l15;
        zf[bt][kh] = *(const v8i*)(z8 + (size_t)row * 64 + kh * 32 + grp * 8);
      }
    }

    const int* pj = Mp + (size_t)nsplit * SPR * 1024 + lane * 8;
    const f32x4 INITC = {-SHIFT2, -SHIFT2, -SHIFT2, -SHIFT2};
    v8i afA[2], afB[2];
    #pragma unroll
    for (int kh = 0; kh < 2; ++kh) afA[kh] = *(const v8i*)(pj + kh * 512);

    // one group: prefetch next frags, 8 MFMA, handoff write, barrier
    auto prodStep = [&](v8i (&CURF)[2], v8i (&NXTF)[2], int buf) {
      const int* pn = pj + 1024;
      #pragma unroll
      for (int kh = 0; kh < 2; ++kh) NXTF[kh] = *(const v8i*)(pn + kh * 512);

      f32x4 acc[4];
      __builtin_amdgcn_s_setprio(1);
      #pragma unroll
      for (int bt = 0; bt < 4; ++bt)
        acc[bt] = __builtin_amdgcn_mfma_scale_f32_16x16x128_f8f6f4(
            CURF[0], zf[bt][0], INITC, 0, 0, 0, SCL1, 0, SCL1);
      #pragma unroll
      for (int bt = 0; bt < 4; ++bt)
        acc[bt] = __builtin_amdgcn_mfma_scale_f32_16x16x128_f8f6f4(
            CURF[1], zf[bt][1], acc[bt], 0, 0, 0, SCL1, 0, SCL1);
      __builtin_amdgcn_s_setprio(0);

      #pragma unroll
      for (int bt = 0; bt < 4; ++bt)
        *(f32x4*)&hand[p][buf][bt][lane][0] = acc[bt];

      __syncthreads();
      pj = pn;
    };

    #pragma unroll 1
    for (int jp = 0; jp < SPR / 2; ++jp) {
      prodStep(afA, afB, 0);    // even group j -> buf 0
      prodStep(afB, afA, 1);    // odd group j  -> buf 1
    }
    // (tail prefetch overshoots into the next range / z8: harmless)
  } else {
    // ---------------- consumer: pure exp2 drain ----------------
    float ssum[4] = {0.f, 0.f, 0.f, 0.f};

    auto drain = [&](int buf) {
      #pragma unroll
      for (int bt = 0; bt < 4; ++bt) {
        f32x4 v = *(const f32x4*)&hand[p][buf][bt][lane][0];
        ssum[bt] += (fexp2(v[0]) + fexp2(v[1])) + (fexp2(v[2]) + fexp2(v[3]));
      }
    };

    #pragma unroll 1
    for (int j = 0; j < SPR; ++j) {
      if (j > 0) drain((j - 1) & 1);   // group j-1, while producer computes j
      __syncthreads();
    }
    drain((SPR - 1) & 1);              // final group

    // 4 lane-groups hold different n-rows for the same b-col
    #pragma unroll
    for (int bt = 0; bt < 4; ++bt) {
      ssum[bt] += __shfl_xor(ssum[bt], 16, 64);
      ssum[bt] += __shfl_xor(ssum[bt], 32, 64);
    }
    if (grp == 0) {
      #pragma unroll
      for (int bt = 0; bt < 4; ++bt) {
        int b = brow0 + bt * 16 + l15;
        lsep[(size_t)b * NSPLIT + nsplit] = ssum[bt];
      }
    }
  }
}

// ---------------------------------------------------------------- kernel C1
// per-row logsumexp partial combine (parallel: 16 blocks x 256 = 4096 rows)
__global__ void rowlse_kernel(const float* __restrict__ lsep, float* __restrict__ rowlse) {
  int r = blockIdx.x * 256 + threadIdx.x;
  float S = 0.f;
  #pragma unroll
  for (int i = 0; i < NSPLIT; ++i) S += lsep[(size_t)r * NSPLIT + i];
  rowlse[r] = SHIFT2 * LN2 + logf(S);
}

// ---------------------------------------------------------------- kernel C2
__global__ void finalize_kernel(const float* __restrict__ rowlse, const float* __restrict__ css,
                                const float* __restrict__ zss, float* __restrict__ out) {
  __shared__ float r1[16], r2[16], r3[16];
  int tid = threadIdx.x;  // 1024
  float sum_lse = 0.f;
  #pragma unroll
  for (int i = 0; i < 4; ++i) sum_lse += rowlse[tid + i * 1024];
  float cs = 0.f, zs = 0.f;
  if (tid < 512) { cs = css[tid]; zs = zss[tid]; }

  sum_lse = waveRedAdd(sum_lse);
  cs = waveRedAdd(cs);
  zs = waveRedAdd(zs);
  int w = tid >> 6, lane = tid & 63;
  if (lane == 0) { r1[w] = sum_lse; r2[w] = cs; r3[w] = zs; }
  __syncthreads();
  if (tid == 0) {
    float sl = 0.f, sc = 0.f, sz = 0.f;
    #pragma unroll
    for (int i = 0; i < 16; ++i) { sl += r1[i]; sc += r2[i]; sz += r3[i]; }
    float hop = -sl / (float)B_ROWS;
    float cons = sc / (float)B_ROWS;
    float reg = 0.01f * sz / (float)B_ROWS;
    out[0] = hop + cons + reg;
    out[1] = hop;
    out[2] = cons;
    out[3] = reg;
  }
}

// ---------------------------------------------------------------------------
extern "C" void kernel_launch(void* const* d_in, const int* in_sizes, int n_in,
                              void* d_out, int out_size, void* d_ws, size_t ws_size,
                              hipStream_t stream) {
  (void)in_sizes; (void)n_in; (void)out_size; (void)ws_size;
  const float* z  = (const float*)d_in[0];
  const float* zn = (const float*)d_in[1];
  const float* M  = (const float*)d_in[2];
  char* ws = (char*)d_ws;
  int* Mp  = (int*)(ws + WS_M_OFF);
  int* z8  = (int*)(ws + WS_Z_OFF);
  float* lsep = (float*)(ws + WS_LSE_OFF);
  float* rowlse = (float*)(ws + WS_ROW_OFF);
  float* css = (float*)(ws + WS_CSS_OFF);
  float* zss = (float*)(ws + WS_ZSS_OFF);

  convert_m_kernel<<<8192, 256, 0, stream>>>(M, Mp);
  prep_z_kernel<<<512, 256, 0, stream>>>(z, zn, z8, css, zss);
  lse_kernel<<<256, 512, 0, stream>>>(Mp, z8, lsep);
  rowlse_kernel<<<16, 256, 0, stream>>>(lsep, rowlse);
  finalize_kernel<<<1, 1024, 0, stream>>>(rowlse, css, zss, (float*)d_out);
}